// Round 20
// baseline (219.999 us; speedup 1.0000x reference)
//
#include <hip/hip_runtime.h>
#include <hip/hip_bf16.h>

#define H_ 4
#define B_ 16
#define T_ 4000
#define E_ 512
#define D_ 512
#define A_ 128
#define C_ 10
#define K_ 101
#define O_ 512
#define TC_ 50
#define CH_ (T_ / TC_)   // 80

typedef __attribute__((ext_vector_type(4))) float f32x4;
typedef __attribute__((ext_vector_type(8)))  short short8;

#define MFMA16(a, b, c) __builtin_amdgcn_mfma_f32_16x16x32_bf16(a, b, c, 0, 0, 0)

#define GLL16(gp, lp) __builtin_amdgcn_global_load_lds( \
    (const __attribute__((address_space(1))) unsigned int*)(gp), \
    (__attribute__((address_space(3))) unsigned int*)(lp), 16, 0, 0)

static __device__ __forceinline__ unsigned short f2bf(float x) {
  unsigned u = __float_as_uint(x);
  unsigned r = (u + 0x7FFFu + ((u >> 16) & 1u)) >> 16;
  return (unsigned short)r;
}
static __device__ __forceinline__ unsigned pk2(float a, float b) {
  return (unsigned)f2bf(a) | ((unsigned)f2bf(b) << 16);
}
static __device__ __forceinline__ unsigned cvtpk(float lo, float hi) {
  unsigned r;
  asm("v_cvt_pk_bf16_f32 %0, %1, %2" : "=v"(r) : "v"(lo), "v"(hi));
  return r;
}
static __device__ __forceinline__ uint4 packbf8(float4 f0, float4 f1) {
  uint4 u;
  u.x = cvtpk(f0.x, f0.y); u.y = cvtpk(f0.z, f0.w);
  u.z = cvtpk(f1.x, f1.y); u.w = cvtpk(f1.z, f1.w);
  return u;
}
static __device__ __forceinline__ float tanh_fast(float x) {
  return 1.0f - 2.0f / (__expf(2.0f * x) + 1.0f);
}
static __device__ __forceinline__ float bfup(unsigned short u) {
  return __uint_as_float((unsigned)u << 16);
}
// data-permutation swizzle: image chunk (row,c) holds data k-block (c^swz(row))
static __device__ __forceinline__ int swz(int r) {
  return (r & 3) ^ ((r >> 2) & 3);
}

// ---------------------------------------------------------------------------
// k_prepconv (merged producers):
//  bid 0..127   : wbs2 = pre-swizzled bf16 Wenc [kt][col=512][4x16B chunks]
//  bid 128      : wattb2 (plain bf16 Watt pad)
//  bid 129..256 : addv4 = 4-way split-K partials of benc + dec_z@Wdec
//  bid 257..1280: location conv -> convpad bf16 [row][h*32B]
__global__ __launch_bounds__(256) void k_prepconv(
    const float* __restrict__ Wenc, const float* __restrict__ Watt,
    const float* __restrict__ dec_z, const float* __restrict__ Wdec,
    const float* __restrict__ benc, const float* __restrict__ att_prev,
    const float* __restrict__ conv_w,
    char* __restrict__ wbs2, char* __restrict__ wattb2,
    float* __restrict__ addv4, char* __restrict__ convpad) {
  __shared__ float ap[256 + K_ - 1 + 3];
  __shared__ float cw[C_ * K_];
  const int bid = blockIdx.x;
  const int tid = threadIdx.x;
  if (bid >= 257) {
    // ---- conv
    const int cid = bid - 257;
    const int bh = cid & 63;
    const int b = bh / H_, h = bh % H_;
    const int t0 = (cid >> 6) * 256;
    const float* src = att_prev + ((size_t)h * B_ + b) * T_;
    for (int i = tid; i < 256 + K_ - 1; i += 256) {
      int tt = t0 - (K_ / 2) + i;
      ap[i] = (tt >= 0 && tt < T_) ? src[tt] : 0.f;
    }
    for (int i = tid; i < C_ * K_; i += 256) cw[i] = conv_w[(size_t)h * C_ * K_ + i];
    __syncthreads();
    const int t = t0 + tid;
    if (t < T_) {
      float s[C_];
#pragma unroll
      for (int c = 0; c < C_; ++c) s[c] = 0.f;
      for (int k = 0; k < K_; ++k) {
        float apv = ap[tid + k];
#pragma unroll
        for (int c = 0; c < C_; ++c) s[c] += cw[c * K_ + k] * apv;
      }
      uint4 u0, u1;
      u0.x = pk2(s[0], s[1]); u0.y = pk2(s[2], s[3]);
      u0.z = pk2(s[4], s[5]); u0.w = pk2(s[6], s[7]);
      u1.x = pk2(s[8], s[9]); u1.y = 0u; u1.z = 0u; u1.w = 0u;
      char* dst = convpad + (size_t)(b * T_ + t) * 128 + h * 32;
      *(uint4*)dst = u0;
      *(uint4*)(dst + 16) = u1;
    }
  } else if (bid < 128) {
    const int c = bid * 256 + tid;       // 16B chunk: [kt][col][cc]
    const int kt = c >> 11;
    const int ci = c & 2047;
    const int col = ci >> 2, cc = ci & 3;
    const int h = col >> 7, a = col & 127;
    const int kk = kt * 32 + ((cc ^ swz(col)) & 3) * 8;
    const float* w = Wenc + ((size_t)h * E_ + kk) * A_ + a;
    uint4 u;
    u.x = pk2(w[0], w[A_]);
    u.y = pk2(w[2 * A_], w[3 * A_]);
    u.z = pk2(w[4 * A_], w[5 * A_]);
    u.w = pk2(w[6 * A_], w[7 * A_]);
    ((uint4*)wbs2)[c] = u;
  } else if (bid == 128) {
#pragma unroll
    for (int q = 0; q < 4; ++q) {
      const int cw2 = q * 256 + tid;      // [h][col][half] 16B chunks
      const int h = cw2 >> 8;
      const int rr = cw2 & 255;
      const int col = rr >> 1, half = rr & 1;
      unsigned short v[8];
#pragma unroll
      for (int j = 0; j < 8; ++j) {
        const int k = half * 8 + j;
        v[j] = (k < C_) ? f2bf(Watt[((size_t)h * C_ + k) * A_ + col]) : (unsigned short)0;
      }
      uint4 u;
      u.x = (unsigned)v[0] | ((unsigned)v[1] << 16);
      u.y = (unsigned)v[2] | ((unsigned)v[3] << 16);
      u.z = (unsigned)v[4] | ((unsigned)v[5] << 16);
      u.w = (unsigned)v[6] | ((unsigned)v[7] << 16);
      ((uint4*)wattb2)[cw2] = u;
    }
  } else {
    const int idx = bid - 129;
    const int b = idx >> 3, h = (idx >> 1) & 3, ks = idx & 1;
    const int a = tid & 127, kh = tid >> 7;
    const int p = ks * 2 + kh;
    const int d0 = p * 128;
    const float* z = dec_z + (size_t)b * D_ + d0;
    const float* w = Wdec + ((size_t)h * D_ + d0) * A_ + a;
    float s = (p == 0) ? benc[h * A_ + a] : 0.f;
#pragma unroll 8
    for (int d = 0; d < 128; ++d) s += z[d] * w[(size_t)d * A_];
    addv4[(((size_t)p * B_ + b) * H_ + h) * A_ + a] = s;
  }
}

// ---------------------------------------------------------------------------
// Fused MFMA — round-16 config restored EXACTLY (measured best end-to-end:
// cached enc loads + cached fire-and-forget encbf stores + lgkmcnt-only
// A-role barrier). nt-load experiment (r18/r19) helped the fused kernel
// (-10us) but cost the tail +24us — net negative; reverted.
__global__ __launch_bounds__(512, 4) void k_fused_e_mfma(
    const float* __restrict__ enc,
    const char*  __restrict__ wbs2,
    const char*  __restrict__ convpad,
    const char*  __restrict__ wattb2,
    const float* __restrict__ addv4,
    const float* __restrict__ gv,
    char* __restrict__ encbf,
    float* __restrict__ e_out) {
  __shared__ char smem[73728];  // A0 0, A1 4096, B0 8192, B1 40960
  const int tid = threadIdx.x;
  const int wv = tid >> 6;
  const int lane = tid & 63, l15 = lane & 15, lg = lane >> 4;
  const int m0 = blockIdx.x * 64;
  const int h = wv >> 1;        // this wave's head
  const bool aRole = (wv < 4);

  f32x4 acc[4][4];
#pragma unroll
  for (int i = 0; i < 4; ++i)
#pragma unroll
    for (int j = 0; j < 4; ++j) acc[i][j] = (f32x4){0.f, 0.f, 0.f, 0.f};

  // fragment read offsets
  int aOff[4], bOff[4];
#pragma unroll
  for (int q = 0; q < 4; ++q) {
    const int row = q * 16 + l15;
    aOff[q] = row * 64 + (((lg ^ swz(row)) & 3) << 4);
    const int col = wv * 64 + q * 16 + l15;
    bOff[q] = col * 64 + (((lg ^ swz(col)) & 3) << 4);
  }

  // A staging geometry (threads 0..255)
  const int arow = tid >> 2, ac = tid & 3;
  const int ks = ((ac ^ swz(arow)) & 3) * 8;
  const float* eR = enc + (size_t)(m0 + arow) * E_ + ks;
  const int wOff = arow * 64 + ac * 16;
  // bf16 enc write-out pointer (linear): row*1024B + ks*2B, advances +64B/kt
  char* ebW = encbf + (size_t)(m0 + arow) * 1024 + ks * 2;
  // B staging geometry (waves 4..7)
  const char* bsrc = wbs2 + (size_t)(wv - 4) * 8192 + lane * 16;
  char* bdstBase = smem + 8192 + (wv - 4) * 8192;

  float4 X0, X1;
  const float* eP = eR + 64;        // X source: enc k-block of kt+2
  const char* bsP = bsrc + 32768;   // B source slab for kt+1

  // ---- prologue: A(0)+X=A(1) | B(0)
  if (aRole) {
    float4 c0 = *(const float4*)eR;
    float4 c1 = *(const float4*)(eR + 4);
    X0 = *(const float4*)(eR + 32);
    X1 = *(const float4*)(eR + 36);
    uint4 pkv = packbf8(c0, c1);
    *(uint4*)(smem + wOff) = pkv;
    *(uint4*)ebW = pkv;               // kt0 bf16 write-out (fire-and-forget)
    asm volatile("s_waitcnt lgkmcnt(0)" ::: "memory");
  } else {
#pragma unroll
    for (int i = 0; i < 8; ++i)
      GLL16(bsrc + i * 1024, bdstBase + i * 1024);
    asm volatile("s_waitcnt vmcnt(0) lgkmcnt(0)" ::: "memory");
  }
  __builtin_amdgcn_sched_barrier(0);
  __builtin_amdgcn_s_barrier();

#pragma unroll 1
  for (int kt = 0; kt < 16; ++kt) {
    const int cur = kt & 1;
    const char* bufA = smem + cur * 4096;
    const char* bufB = smem + 8192 + cur * 32768;

    // (1) B prefetch kt+1 (waves 4-7), carried pointer
    if (!aRole && kt < 15) {
      char* d = smem + 8192 + (cur ^ 1) * 32768 + (wv - 4) * 8192;
#pragma unroll
      for (int i = 0; i < 8; ++i)
        GLL16(bsP + i * 1024, d + i * 1024);
    }
    __builtin_amdgcn_sched_barrier(0);

    // (2) frags + 16 MFMA
    short8 aF[4];
#pragma unroll
    for (int q = 0; q < 4; ++q) aF[q] = *(const short8*)(bufA + aOff[q]);
#pragma unroll
    for (int qn = 0; qn < 4; ++qn) {
      short8 bF = *(const short8*)(bufB + bOff[qn]);
#pragma unroll
      for (int qm = 0; qm < 4; ++qm)
        acc[qm][qn] = MFMA16(aF[qm], bF, acc[qm][qn]);
    }

    // (3) A write kt+1 from X (LDS + fire-and-forget cached global store)
    if (aRole) {
      if (kt < 15) {
        uint4 pkv = packbf8(X0, X1);
        *(uint4*)(smem + (cur ^ 1) * 4096 + wOff) = pkv;
        *(uint4*)(ebW + (kt + 1) * 64) = pkv;
      }
      if (kt < 14) {
        X0 = *(const float4*)eP;
        X1 = *(const float4*)(eP + 4);
        eP += 32;
      }
    } else {
      bsP += 32768;
    }

    // (4) role-counted barrier: A-role needs ONLY lgkmcnt(0) (stores stay
    //     in flight; X loads are compiler-waited at their use)
    if (kt < 14) {
      if (aRole)
        asm volatile("s_waitcnt lgkmcnt(0)" ::: "memory");
      else
        asm volatile("s_waitcnt vmcnt(0) lgkmcnt(0)" ::: "memory");
    } else {
      asm volatile("s_waitcnt vmcnt(0) lgkmcnt(0)" ::: "memory");
    }
    __builtin_amdgcn_sched_barrier(0);
    __builtin_amdgcn_s_barrier();
  }

  // ---- conv MFMA step (K=32, upper 16 k zero)
  {
    short8 zf;
#pragma unroll
    for (int i = 0; i < 8; ++i) zf[i] = 0;
    short8 cf[4], wf[4];
#pragma unroll
    for (int q = 0; q < 4; ++q) { cf[q] = zf; wf[q] = zf; }
    if (lg < 2) {
#pragma unroll
      for (int q = 0; q < 4; ++q) {
        const int row = m0 + q * 16 + l15;
        cf[q] = *(const short8*)(convpad + (size_t)row * 128 + h * 32 + lg * 16);
        const int col = (wv & 1) * 64 + q * 16 + l15;   // head-local col
        wf[q] = *(const short8*)(wattb2 + ((size_t)h * 128 + col) * 32 + lg * 16);
      }
    }
#pragma unroll
    for (int qm = 0; qm < 4; ++qm)
#pragma unroll
      for (int qn = 0; qn < 4; ++qn)
        acc[qm][qn] = MFMA16(cf[qm], wf[qn], acc[qm][qn]);
  }

  // ---- epilogue: + addv, tanh, dot gv, 16-lane reduce -> Pb, cross-wave sum
  {
    const unsigned b0w = (unsigned)m0 / 4000u;
    const unsigned b1w = (unsigned)(m0 + 63) / 4000u;
    float av0[4], av1[4], gvr[4];
#pragma unroll
    for (int qn = 0; qn < 4; ++qn) {
      const int col = (wv & 1) * 64 + qn * 16 + l15;
      const int i0 = (int)b0w * 512 + h * 128 + col;
      const int i1 = (int)b1w * 512 + h * 128 + col;
      av0[qn] = addv4[i0] + addv4[8192 + i0] + addv4[16384 + i0] + addv4[24576 + i0];
      av1[qn] = addv4[i1] + addv4[8192 + i1] + addv4[16384 + i1] + addv4[24576 + i1];
      gvr[qn] = gv[h * 128 + col];
    }
    float* Pb = (float*)smem;   // 8 waves x 64 rows (A region, reads all done)
#pragma unroll
    for (int qm = 0; qm < 4; ++qm) {
#pragma unroll
      for (int r = 0; r < 4; ++r) {
        const int rowLocal = qm * 16 + lg * 4 + r;
        const unsigned brow = (unsigned)(m0 + rowLocal);
        const unsigned bb = brow / 4000u;
        const int sel = (bb != b0w);
        float s = 0.f;
#pragma unroll
        for (int qn = 0; qn < 4; ++qn)
          s += gvr[qn] * tanh_fast(acc[qm][qn][r] + (sel ? av1[qn] : av0[qn]));
        s += __shfl_xor(s, 1);
        s += __shfl_xor(s, 2);
        s += __shfl_xor(s, 4);
        s += __shfl_xor(s, 8);
        if (l15 == 0) Pb[wv * 64 + rowLocal] = s;
      }
    }
  }
  __syncthreads();
  if (tid < 256) {
    const float* Pb = (const float*)smem;
    const int hh = tid >> 6, r = tid & 63;
    const float ev = Pb[(hh * 2) * 64 + r] + Pb[(hh * 2 + 1) * 64 + r];
    const unsigned brow = (unsigned)(m0 + r);
    const unsigned bb = brow / 4000u;
    const unsigned tt = brow - bb * 4000u;
    e_out[((size_t)bb * H_ + hh) * T_ + tt] = ev;
  }
}

// ---------------------------------------------------------------------------
__global__ __launch_bounds__(256) void k_msum(const float* __restrict__ e_in,
                                              float2* __restrict__ msum) {
  const int bh = blockIdx.x;
  const float* er = e_in + (size_t)bh * T_;
  __shared__ float red[256];
  const int tid = threadIdx.x;
  float m = -1e30f;
  for (int t = tid; t < T_; t += 256) m = fmaxf(m, er[t]);
  red[tid] = m;
  __syncthreads();
  for (int s = 128; s > 0; s >>= 1) {
    if (tid < s) red[tid] = fmaxf(red[tid], red[tid + s]);
    __syncthreads();
  }
  m = red[0];
  __syncthreads();
  float sum = 0.f;
  for (int t = tid; t < T_; t += 256) sum += __expf(er[t] - m);
  red[tid] = sum;
  __syncthreads();
  for (int s = 128; s > 0; s >>= 1) {
    if (tid < s) red[tid] += red[tid + s];
    __syncthreads();
  }
  if (tid == 0) msum[bh] = make_float2(m, 1.0f / red[0]);
}

// ---------------------------------------------------------------------------
// ctx + inline softmax, 512 threads (4 row-groups of 20). Reads bf16 encbf
// (64MB, L3-hot — written cached by the fused kernel) instead of fp32 enc.
__global__ __launch_bounds__(512) void k_ctx(const char* __restrict__ encbf,
                                             const float* __restrict__ e_in,
                                             const float2* __restrict__ msum,
                                             float* __restrict__ wout,
                                             float* __restrict__ partial) {
  const int b = blockIdx.x, tc = blockIdx.y;
  const int t0 = tc * CH_;
  const int tid = threadIdx.x;
  const int grp = tid >> 7, lt = tid & 127;
  __shared__ float wls[H_ * CH_];
  __shared__ float4 red[3][4][128];   // 24KB
  for (int i = tid; i < H_ * CH_; i += 512) {
    const int h = i / CH_, tt = i - h * CH_;
    const float2 ms = msum[b * H_ + h];
    const float w = __expf(e_in[((size_t)b * H_ + h) * T_ + t0 + tt] - ms.x) * ms.y;
    wls[i] = w;
    wout[((size_t)h * B_ + b) * T_ + t0 + tt] = w;
  }
  __syncthreads();
  float4 a0 = {0,0,0,0}, a1 = {0,0,0,0}, a2 = {0,0,0,0}, a3 = {0,0,0,0};
  const unsigned short* eb = (const unsigned short*)encbf;
  const int tg = grp * 20;
  const size_t ebase = ((size_t)b * T_ + t0 + tg) * 512 + lt * 4;  // bf16 units
#pragma unroll 5
  for (int tt = 0; tt < 20; ++tt) {
    const ushort4 v = *(const ushort4*)(eb + ebase + (size_t)tt * 512);
    const float4 x = {bfup(v.x), bfup(v.y), bfup(v.z), bfup(v.w)};
    const float w0 = wls[tg + tt];
    const float w1 = wls[CH_ + tg + tt];
    const float w2 = wls[2 * CH_ + tg + tt];
    const float w3 = wls[3 * CH_ + tg + tt];
    a0.x += w0 * x.x; a0.y += w0 * x.y; a0.z += w0 * x.z; a0.w += w0 * x.w;
    a1.x += w1 * x.x; a1.y += w1 * x.y; a1.z += w1 * x.z; a1.w += w1 * x.w;
    a2.x += w2 * x.x; a2.y += w2 * x.y; a2.z += w2 * x.z; a2.w += w2 * x.w;
    a3.x += w3 * x.x; a3.y += w3 * x.y; a3.z += w3 * x.z; a3.w += w3 * x.w;
  }
  if (grp > 0) {
    red[grp - 1][0][lt] = a0;
    red[grp - 1][1][lt] = a1;
    red[grp - 1][2][lt] = a2;
    red[grp - 1][3][lt] = a3;
  }
  __syncthreads();
  if (grp == 0) {
#pragma unroll
    for (int g = 0; g < 3; ++g) {
      const float4 r0 = red[g][0][lt], r1 = red[g][1][lt];
      const float4 r2 = red[g][2][lt], r3 = red[g][3][lt];
      a0.x += r0.x; a0.y += r0.y; a0.z += r0.z; a0.w += r0.w;
      a1.x += r1.x; a1.y += r1.y; a1.z += r1.z; a1.w += r1.w;
      a2.x += r2.x; a2.y += r2.y; a2.z += r2.z; a2.w += r2.w;
      a3.x += r3.x; a3.y += r3.y; a3.z += r3.z; a3.w += r3.w;
    }
    float4* p4 = (float4*)partial;
    const size_t pbase = (((size_t)tc * B_ + b) * H_) * 128 + lt;
    p4[pbase] = a0;
    p4[pbase + 128] = a1;
    p4[pbase + 256] = a2;
    p4[pbase + 384] = a3;
  }
}

// ---------------------------------------------------------------------------
// merged output projection: out[b,o] = bo[o] + sum_he c[b,he]*Wo[he,o],
// with the tc-reduction of `partial` fused in via LDS chunk staging.
// grid (B, O/256), 256 thr. Replaces k_out_part + k_out_fin (saves the
// p2 round-trip + one launch gap). Does NOT touch the fused kernel.
__global__ __launch_bounds__(256) void k_out(const float* __restrict__ partial,
                                             const float* __restrict__ Wo,
                                             const float* __restrict__ bo,
                                             float* __restrict__ out) {
  const int b = blockIdx.x;
  const int o = blockIdx.y * 256 + threadIdx.x;
  __shared__ float cS[256];
  float acc = bo[o];
#pragma unroll 1
  for (int kc = 0; kc < 8; ++kc) {
    const int he0 = kc * 256;
    float s = 0.f;
#pragma unroll
    for (int tc = 0; tc < TC_; ++tc)
      s += partial[((size_t)tc * B_ + b) * (H_ * E_) + he0 + threadIdx.x];
    __syncthreads();
    cS[threadIdx.x] = s;
    __syncthreads();
#pragma unroll 8
    for (int i = 0; i < 256; ++i) acc += cS[i] * Wo[(size_t)(he0 + i) * O_ + o];
  }
  out[b * O_ + o] = acc;
}

// ---------------------------------------------------------------------------
extern "C" void kernel_launch(void* const* d_in, const int* in_sizes, int n_in,
                              void* d_out, int out_size, void* d_ws, size_t ws_size,
                              hipStream_t stream) {
  (void)in_sizes; (void)n_in; (void)out_size; (void)ws_size;
  const float* enc      = (const float*)d_in[0];
  // d_in[1] = enc_len : unused by the reference
  const float* dec_z    = (const float*)d_in[2];
  const float* att_prev = (const float*)d_in[3];
  const float* Wenc     = (const float*)d_in[4];
  const float* benc     = (const float*)d_in[5];
  const float* Wdec     = (const float*)d_in[6];
  const float* Watt     = (const float*)d_in[7];
  const float* conv_w   = (const float*)d_in[8];
  const float* gv       = (const float*)d_in[9];
  const float* Wo       = (const float*)d_in[10];
  const float* bo       = (const float*)d_in[11];

  float* out  = (float*)d_out;
  float* wout = out + B_ * O_;  // ws [H,B,T]

  char* wsb = (char*)d_ws;
  float*  e_buf   = (float*)(wsb);               // 1,024,000 B
  char*   convpad = wsb + 1024000;               // 8,192,000 B
  char*   wbs2    = wsb + 9216000;               //   524,288 B
  char*   wattb2  = wsb + 9740288;               //    16,384 B
  float*  addv4   = (float*)(wsb + 9756672);     //   131,072 B
  float2* msum    = (float2*)(wsb + 9887744);    //       512 B
  float*  partial = (float*)(wsb + 9888256);     // 6,553,600 B
  char*   encbf   = wsb + 16704000;              // 65,536,000 B (bf16 enc)

  hipLaunchKernelGGL(k_prepconv, dim3(1281), dim3(256), 0, stream,
                     Wenc, Watt, dec_z, Wdec, benc, att_prev, conv_w,
                     wbs2, wattb2, addv4, convpad);
  hipLaunchKernelGGL(k_fused_e_mfma, dim3(1000), dim3(512), 0, stream,
                     enc, wbs2, convpad, wattb2, addv4, gv, encbf, e_buf);
  hipLaunchKernelGGL(k_msum, dim3(B_ * H_), dim3(256), 0, stream, e_buf, msum);
  hipLaunchKernelGGL(k_ctx, dim3(B_, TC_), dim3(512), 0, stream,
                     encbf, e_buf, msum, wout, partial);
  hipLaunchKernelGGL(k_out, dim3(B_, O_ / 256), dim3(256), 0, stream,
                     partial, Wo, bo, out);
}

// Round 21
// 128.412 us; speedup vs baseline: 1.7132x; 1.7132x over previous
//
#include <hip/hip_runtime.h>
#include <hip/hip_bf16.h>

#define H_ 4
#define B_ 16
#define T_ 4000
#define E_ 512
#define D_ 512
#define A_ 128
#define C_ 10
#define K_ 101
#define O_ 512
#define TC_ 50
#define CH_ (T_ / TC_)   // 80

typedef __attribute__((ext_vector_type(4))) float f32x4;
typedef __attribute__((ext_vector_type(8)))  short short8;

#define MFMA16(a, b, c) __builtin_amdgcn_mfma_f32_16x16x32_bf16(a, b, c, 0, 0, 0)

#define GLL16(gp, lp) __builtin_amdgcn_global_load_lds( \
    (const __attribute__((address_space(1))) unsigned int*)(gp), \
    (__attribute__((address_space(3))) unsigned int*)(lp), 16, 0, 0)

static __device__ __forceinline__ unsigned short f2bf(float x) {
  unsigned u = __float_as_uint(x);
  unsigned r = (u + 0x7FFFu + ((u >> 16) & 1u)) >> 16;
  return (unsigned short)r;
}
static __device__ __forceinline__ unsigned pk2(float a, float b) {
  return (unsigned)f2bf(a) | ((unsigned)f2bf(b) << 16);
}
static __device__ __forceinline__ unsigned cvtpk(float lo, float hi) {
  unsigned r;
  asm("v_cvt_pk_bf16_f32 %0, %1, %2" : "=v"(r) : "v"(lo), "v"(hi));
  return r;
}
static __device__ __forceinline__ uint4 packbf8(float4 f0, float4 f1) {
  uint4 u;
  u.x = cvtpk(f0.x, f0.y); u.y = cvtpk(f0.z, f0.w);
  u.z = cvtpk(f1.x, f1.y); u.w = cvtpk(f1.z, f1.w);
  return u;
}
static __device__ __forceinline__ float tanh_fast(float x) {
  return 1.0f - 2.0f / (__expf(2.0f * x) + 1.0f);
}
static __device__ __forceinline__ float bfup(unsigned short u) {
  return __uint_as_float((unsigned)u << 16);
}
// data-permutation swizzle: image chunk (row,c) holds data k-block (c^swz(row))
static __device__ __forceinline__ int swz(int r) {
  return (r & 3) ^ ((r >> 2) & 3);
}

// ---------------------------------------------------------------------------
// k_prepconv (merged producers):
//  bid 0..127   : wbs2 = pre-swizzled bf16 Wenc [kt][col=512][4x16B chunks]
//  bid 128      : wattb2 (plain bf16 Watt pad)
//  bid 129..256 : addv4 = 4-way split-K partials of benc + dec_z@Wdec
//  bid 257..1280: location conv -> convpad bf16 [row][h*32B]
__global__ __launch_bounds__(256) void k_prepconv(
    const float* __restrict__ Wenc, const float* __restrict__ Watt,
    const float* __restrict__ dec_z, const float* __restrict__ Wdec,
    const float* __restrict__ benc, const float* __restrict__ att_prev,
    const float* __restrict__ conv_w,
    char* __restrict__ wbs2, char* __restrict__ wattb2,
    float* __restrict__ addv4, char* __restrict__ convpad) {
  __shared__ float ap[256 + K_ - 1 + 3];
  __shared__ float cw[C_ * K_];
  const int bid = blockIdx.x;
  const int tid = threadIdx.x;
  if (bid >= 257) {
    // ---- conv
    const int cid = bid - 257;
    const int bh = cid & 63;
    const int b = bh / H_, h = bh % H_;
    const int t0 = (cid >> 6) * 256;
    const float* src = att_prev + ((size_t)h * B_ + b) * T_;
    for (int i = tid; i < 256 + K_ - 1; i += 256) {
      int tt = t0 - (K_ / 2) + i;
      ap[i] = (tt >= 0 && tt < T_) ? src[tt] : 0.f;
    }
    for (int i = tid; i < C_ * K_; i += 256) cw[i] = conv_w[(size_t)h * C_ * K_ + i];
    __syncthreads();
    const int t = t0 + tid;
    if (t < T_) {
      float s[C_];
#pragma unroll
      for (int c = 0; c < C_; ++c) s[c] = 0.f;
      for (int k = 0; k < K_; ++k) {
        float apv = ap[tid + k];
#pragma unroll
        for (int c = 0; c < C_; ++c) s[c] += cw[c * K_ + k] * apv;
      }
      uint4 u0, u1;
      u0.x = pk2(s[0], s[1]); u0.y = pk2(s[2], s[3]);
      u0.z = pk2(s[4], s[5]); u0.w = pk2(s[6], s[7]);
      u1.x = pk2(s[8], s[9]); u1.y = 0u; u1.z = 0u; u1.w = 0u;
      char* dst = convpad + (size_t)(b * T_ + t) * 128 + h * 32;
      *(uint4*)dst = u0;
      *(uint4*)(dst + 16) = u1;
    }
  } else if (bid < 128) {
    const int c = bid * 256 + tid;       // 16B chunk: [kt][col][cc]
    const int kt = c >> 11;
    const int ci = c & 2047;
    const int col = ci >> 2, cc = ci & 3;
    const int h = col >> 7, a = col & 127;
    const int kk = kt * 32 + ((cc ^ swz(col)) & 3) * 8;
    const float* w = Wenc + ((size_t)h * E_ + kk) * A_ + a;
    uint4 u;
    u.x = pk2(w[0], w[A_]);
    u.y = pk2(w[2 * A_], w[3 * A_]);
    u.z = pk2(w[4 * A_], w[5 * A_]);
    u.w = pk2(w[6 * A_], w[7 * A_]);
    ((uint4*)wbs2)[c] = u;
  } else if (bid == 128) {
#pragma unroll
    for (int q = 0; q < 4; ++q) {
      const int cw2 = q * 256 + tid;      // [h][col][half] 16B chunks
      const int h = cw2 >> 8;
      const int rr = cw2 & 255;
      const int col = rr >> 1, half = rr & 1;
      unsigned short v[8];
#pragma unroll
      for (int j = 0; j < 8; ++j) {
        const int k = half * 8 + j;
        v[j] = (k < C_) ? f2bf(Watt[((size_t)h * C_ + k) * A_ + col]) : (unsigned short)0;
      }
      uint4 u;
      u.x = (unsigned)v[0] | ((unsigned)v[1] << 16);
      u.y = (unsigned)v[2] | ((unsigned)v[3] << 16);
      u.z = (unsigned)v[4] | ((unsigned)v[5] << 16);
      u.w = (unsigned)v[6] | ((unsigned)v[7] << 16);
      ((uint4*)wattb2)[cw2] = u;
    }
  } else {
    const int idx = bid - 129;
    const int b = idx >> 3, h = (idx >> 1) & 3, ks = idx & 1;
    const int a = tid & 127, kh = tid >> 7;
    const int p = ks * 2 + kh;
    const int d0 = p * 128;
    const float* z = dec_z + (size_t)b * D_ + d0;
    const float* w = Wdec + ((size_t)h * D_ + d0) * A_ + a;
    float s = (p == 0) ? benc[h * A_ + a] : 0.f;
#pragma unroll 8
    for (int d = 0; d < 128; ++d) s += z[d] * w[(size_t)d * A_];
    addv4[(((size_t)p * B_ + b) * H_ + h) * A_ + a] = s;
  }
}

// ---------------------------------------------------------------------------
// Fused MFMA — round-16 config (best measured end-to-end: 130.1us total):
// cached enc loads + cached fire-and-forget encbf stores + lgkmcnt-only
// A-role barrier. Merged heads, role-split staging, 2 blocks/CU,
// acc[4][4]=64 AGPR. Do not edit without an A/B tripwire (rule #19).
__global__ __launch_bounds__(512, 4) void k_fused_e_mfma(
    const float* __restrict__ enc,
    const char*  __restrict__ wbs2,
    const char*  __restrict__ convpad,
    const char*  __restrict__ wattb2,
    const float* __restrict__ addv4,
    const float* __restrict__ gv,
    char* __restrict__ encbf,
    float* __restrict__ e_out) {
  __shared__ char smem[73728];  // A0 0, A1 4096, B0 8192, B1 40960
  const int tid = threadIdx.x;
  const int wv = tid >> 6;
  const int lane = tid & 63, l15 = lane & 15, lg = lane >> 4;
  const int m0 = blockIdx.x * 64;
  const int h = wv >> 1;        // this wave's head
  const bool aRole = (wv < 4);

  f32x4 acc[4][4];
#pragma unroll
  for (int i = 0; i < 4; ++i)
#pragma unroll
    for (int j = 0; j < 4; ++j) acc[i][j] = (f32x4){0.f, 0.f, 0.f, 0.f};

  // fragment read offsets
  int aOff[4], bOff[4];
#pragma unroll
  for (int q = 0; q < 4; ++q) {
    const int row = q * 16 + l15;
    aOff[q] = row * 64 + (((lg ^ swz(row)) & 3) << 4);
    const int col = wv * 64 + q * 16 + l15;
    bOff[q] = col * 64 + (((lg ^ swz(col)) & 3) << 4);
  }

  // A staging geometry (threads 0..255)
  const int arow = tid >> 2, ac = tid & 3;
  const int ks = ((ac ^ swz(arow)) & 3) * 8;
  const float* eR = enc + (size_t)(m0 + arow) * E_ + ks;
  const int wOff = arow * 64 + ac * 16;
  // bf16 enc write-out pointer (linear): row*1024B + ks*2B, advances +64B/kt
  char* ebW = encbf + (size_t)(m0 + arow) * 1024 + ks * 2;
  // B staging geometry (waves 4..7)
  const char* bsrc = wbs2 + (size_t)(wv - 4) * 8192 + lane * 16;
  char* bdstBase = smem + 8192 + (wv - 4) * 8192;

  float4 X0, X1;
  const float* eP = eR + 64;        // X source: enc k-block of kt+2
  const char* bsP = bsrc + 32768;   // B source slab for kt+1

  // ---- prologue: A(0)+X=A(1) | B(0)
  if (aRole) {
    float4 c0 = *(const float4*)eR;
    float4 c1 = *(const float4*)(eR + 4);
    X0 = *(const float4*)(eR + 32);
    X1 = *(const float4*)(eR + 36);
    uint4 pkv = packbf8(c0, c1);
    *(uint4*)(smem + wOff) = pkv;
    *(uint4*)ebW = pkv;               // kt0 bf16 write-out (fire-and-forget)
    asm volatile("s_waitcnt lgkmcnt(0)" ::: "memory");
  } else {
#pragma unroll
    for (int i = 0; i < 8; ++i)
      GLL16(bsrc + i * 1024, bdstBase + i * 1024);
    asm volatile("s_waitcnt vmcnt(0) lgkmcnt(0)" ::: "memory");
  }
  __builtin_amdgcn_sched_barrier(0);
  __builtin_amdgcn_s_barrier();

#pragma unroll 1
  for (int kt = 0; kt < 16; ++kt) {
    const int cur = kt & 1;
    const char* bufA = smem + cur * 4096;
    const char* bufB = smem + 8192 + cur * 32768;

    // (1) B prefetch kt+1 (waves 4-7), carried pointer
    if (!aRole && kt < 15) {
      char* d = smem + 8192 + (cur ^ 1) * 32768 + (wv - 4) * 8192;
#pragma unroll
      for (int i = 0; i < 8; ++i)
        GLL16(bsP + i * 1024, d + i * 1024);
    }
    __builtin_amdgcn_sched_barrier(0);

    // (2) frags + 16 MFMA
    short8 aF[4];
#pragma unroll
    for (int q = 0; q < 4; ++q) aF[q] = *(const short8*)(bufA + aOff[q]);
#pragma unroll
    for (int qn = 0; qn < 4; ++qn) {
      short8 bF = *(const short8*)(bufB + bOff[qn]);
#pragma unroll
      for (int qm = 0; qm < 4; ++qm)
        acc[qm][qn] = MFMA16(aF[qm], bF, acc[qm][qn]);
    }

    // (3) A write kt+1 from X (LDS + fire-and-forget cached global store)
    if (aRole) {
      if (kt < 15) {
        uint4 pkv = packbf8(X0, X1);
        *(uint4*)(smem + (cur ^ 1) * 4096 + wOff) = pkv;
        *(uint4*)(ebW + (kt + 1) * 64) = pkv;
      }
      if (kt < 14) {
        X0 = *(const float4*)eP;
        X1 = *(const float4*)(eP + 4);
        eP += 32;
      }
    } else {
      bsP += 32768;
    }

    // (4) role-counted barrier: A-role needs ONLY lgkmcnt(0) (stores stay
    //     in flight; X loads are compiler-waited at their use)
    if (kt < 14) {
      if (aRole)
        asm volatile("s_waitcnt lgkmcnt(0)" ::: "memory");
      else
        asm volatile("s_waitcnt vmcnt(0) lgkmcnt(0)" ::: "memory");
    } else {
      asm volatile("s_waitcnt vmcnt(0) lgkmcnt(0)" ::: "memory");
    }
    __builtin_amdgcn_sched_barrier(0);
    __builtin_amdgcn_s_barrier();
  }

  // ---- conv MFMA step (K=32, upper 16 k zero)
  {
    short8 zf;
#pragma unroll
    for (int i = 0; i < 8; ++i) zf[i] = 0;
    short8 cf[4], wf[4];
#pragma unroll
    for (int q = 0; q < 4; ++q) { cf[q] = zf; wf[q] = zf; }
    if (lg < 2) {
#pragma unroll
      for (int q = 0; q < 4; ++q) {
        const int row = m0 + q * 16 + l15;
        cf[q] = *(const short8*)(convpad + (size_t)row * 128 + h * 32 + lg * 16);
        const int col = (wv & 1) * 64 + q * 16 + l15;   // head-local col
        wf[q] = *(const short8*)(wattb2 + ((size_t)h * 128 + col) * 32 + lg * 16);
      }
    }
#pragma unroll
    for (int qm = 0; qm < 4; ++qm)
#pragma unroll
      for (int qn = 0; qn < 4; ++qn)
        acc[qm][qn] = MFMA16(cf[qm], wf[qn], acc[qm][qn]);
  }

  // ---- epilogue: + addv, tanh, dot gv, 16-lane reduce -> Pb, cross-wave sum
  {
    const unsigned b0w = (unsigned)m0 / 4000u;
    const unsigned b1w = (unsigned)(m0 + 63) / 4000u;
    float av0[4], av1[4], gvr[4];
#pragma unroll
    for (int qn = 0; qn < 4; ++qn) {
      const int col = (wv & 1) * 64 + qn * 16 + l15;
      const int i0 = (int)b0w * 512 + h * 128 + col;
      const int i1 = (int)b1w * 512 + h * 128 + col;
      av0[qn] = addv4[i0] + addv4[8192 + i0] + addv4[16384 + i0] + addv4[24576 + i0];
      av1[qn] = addv4[i1] + addv4[8192 + i1] + addv4[16384 + i1] + addv4[24576 + i1];
      gvr[qn] = gv[h * 128 + col];
    }
    float* Pb = (float*)smem;   // 8 waves x 64 rows (A region, reads all done)
#pragma unroll
    for (int qm = 0; qm < 4; ++qm) {
#pragma unroll
      for (int r = 0; r < 4; ++r) {
        const int rowLocal = qm * 16 + lg * 4 + r;
        const unsigned brow = (unsigned)(m0 + rowLocal);
        const unsigned bb = brow / 4000u;
        const int sel = (bb != b0w);
        float s = 0.f;
#pragma unroll
        for (int qn = 0; qn < 4; ++qn)
          s += gvr[qn] * tanh_fast(acc[qm][qn][r] + (sel ? av1[qn] : av0[qn]));
        s += __shfl_xor(s, 1);
        s += __shfl_xor(s, 2);
        s += __shfl_xor(s, 4);
        s += __shfl_xor(s, 8);
        if (l15 == 0) Pb[wv * 64 + rowLocal] = s;
      }
    }
  }
  __syncthreads();
  if (tid < 256) {
    const float* Pb = (const float*)smem;
    const int hh = tid >> 6, r = tid & 63;
    const float ev = Pb[(hh * 2) * 64 + r] + Pb[(hh * 2 + 1) * 64 + r];
    const unsigned brow = (unsigned)(m0 + r);
    const unsigned bb = brow / 4000u;
    const unsigned tt = brow - bb * 4000u;
    e_out[((size_t)bb * H_ + hh) * T_ + tt] = ev;
  }
}

// ---------------------------------------------------------------------------
__global__ __launch_bounds__(256) void k_msum(const float* __restrict__ e_in,
                                              float2* __restrict__ msum) {
  const int bh = blockIdx.x;
  const float* er = e_in + (size_t)bh * T_;
  __shared__ float red[256];
  const int tid = threadIdx.x;
  float m = -1e30f;
  for (int t = tid; t < T_; t += 256) m = fmaxf(m, er[t]);
  red[tid] = m;
  __syncthreads();
  for (int s = 128; s > 0; s >>= 1) {
    if (tid < s) red[tid] = fmaxf(red[tid], red[tid + s]);
    __syncthreads();
  }
  m = red[0];
  __syncthreads();
  float sum = 0.f;
  for (int t = tid; t < T_; t += 256) sum += __expf(er[t] - m);
  red[tid] = sum;
  __syncthreads();
  for (int s = 128; s > 0; s >>= 1) {
    if (tid < s) red[tid] += red[tid + s];
    __syncthreads();
  }
  if (tid == 0) msum[bh] = make_float2(m, 1.0f / red[0]);
}

// ---------------------------------------------------------------------------
// ctx + inline softmax, 512 threads (4 row-groups of 20). Reads bf16 encbf
// (64MB, L3-hot — written cached by the fused kernel) instead of fp32 enc.
__global__ __launch_bounds__(512) void k_ctx(const char* __restrict__ encbf,
                                             const float* __restrict__ e_in,
                                             const float2* __restrict__ msum,
                                             float* __restrict__ wout,
                                             float* __restrict__ partial) {
  const int b = blockIdx.x, tc = blockIdx.y;
  const int t0 = tc * CH_;
  const int tid = threadIdx.x;
  const int grp = tid >> 7, lt = tid & 127;
  __shared__ float wls[H_ * CH_];
  __shared__ float4 red[3][4][128];   // 24KB
  for (int i = tid; i < H_ * CH_; i += 512) {
    const int h = i / CH_, tt = i - h * CH_;
    const float2 ms = msum[b * H_ + h];
    const float w = __expf(e_in[((size_t)b * H_ + h) * T_ + t0 + tt] - ms.x) * ms.y;
    wls[i] = w;
    wout[((size_t)h * B_ + b) * T_ + t0 + tt] = w;
  }
  __syncthreads();
  float4 a0 = {0,0,0,0}, a1 = {0,0,0,0}, a2 = {0,0,0,0}, a3 = {0,0,0,0};
  const unsigned short* eb = (const unsigned short*)encbf;
  const int tg = grp * 20;
  const size_t ebase = ((size_t)b * T_ + t0 + tg) * 512 + lt * 4;  // bf16 units
#pragma unroll 5
  for (int tt = 0; tt < 20; ++tt) {
    const ushort4 v = *(const ushort4*)(eb + ebase + (size_t)tt * 512);
    const float4 x = {bfup(v.x), bfup(v.y), bfup(v.z), bfup(v.w)};
    const float w0 = wls[tg + tt];
    const float w1 = wls[CH_ + tg + tt];
    const float w2 = wls[2 * CH_ + tg + tt];
    const float w3 = wls[3 * CH_ + tg + tt];
    a0.x += w0 * x.x; a0.y += w0 * x.y; a0.z += w0 * x.z; a0.w += w0 * x.w;
    a1.x += w1 * x.x; a1.y += w1 * x.y; a1.z += w1 * x.z; a1.w += w1 * x.w;
    a2.x += w2 * x.x; a2.y += w2 * x.y; a2.z += w2 * x.z; a2.w += w2 * x.w;
    a3.x += w3 * x.x; a3.y += w3 * x.y; a3.z += w3 * x.z; a3.w += w3 * x.w;
  }
  if (grp > 0) {
    red[grp - 1][0][lt] = a0;
    red[grp - 1][1][lt] = a1;
    red[grp - 1][2][lt] = a2;
    red[grp - 1][3][lt] = a3;
  }
  __syncthreads();
  if (grp == 0) {
#pragma unroll
    for (int g = 0; g < 3; ++g) {
      const float4 r0 = red[g][0][lt], r1 = red[g][1][lt];
      const float4 r2 = red[g][2][lt], r3 = red[g][3][lt];
      a0.x += r0.x; a0.y += r0.y; a0.z += r0.z; a0.w += r0.w;
      a1.x += r1.x; a1.y += r1.y; a1.z += r1.z; a1.w += r1.w;
      a2.x += r2.x; a2.y += r2.y; a2.z += r2.z; a2.w += r2.w;
      a3.x += r3.x; a3.y += r3.y; a3.z += r3.z; a3.w += r3.w;
    }
    float4* p4 = (float4*)partial;
    const size_t pbase = (((size_t)tc * B_ + b) * H_) * 128 + lt;
    p4[pbase] = a0;
    p4[pbase + 128] = a1;
    p4[pbase + 256] = a2;
    p4[pbase + 384] = a3;
  }
}

// ---------------------------------------------------------------------------
// out partials with fused tc-reduction: p2[kc][b][o]  (split-K z-dim = the
// parallelism; round-20's 32-block merge ran at 1.4% occupancy, 147us)
__global__ __launch_bounds__(256) void k_out_part(const float* __restrict__ partial,
                                                  const float* __restrict__ Wo,
                                                  float* __restrict__ p2) {
  const int b = blockIdx.x;
  const int o = blockIdx.y * 256 + threadIdx.x;
  const int kc = blockIdx.z;
  __shared__ float cS[256];
  const int he0 = kc * 256;
  {
    float s = 0.f;
#pragma unroll
    for (int tc = 0; tc < TC_; ++tc)
      s += partial[((size_t)tc * B_ + b) * (H_ * E_) + he0 + threadIdx.x];
    cS[threadIdx.x] = s;
  }
  __syncthreads();
  float s = 0.f;
#pragma unroll 8
  for (int i = 0; i < 256; ++i) s += cS[i] * Wo[(size_t)(he0 + i) * O_ + o];
  p2[((size_t)kc * B_ + b) * O_ + o] = s;
}

__global__ __launch_bounds__(512) void k_out_fin(const float* __restrict__ p2,
                                                 const float* __restrict__ bo,
                                                 float* __restrict__ out) {
  const int b = blockIdx.x, o = threadIdx.x;
  float s = bo[o];
#pragma unroll
  for (int kc = 0; kc < 8; ++kc) s += p2[((size_t)kc * B_ + b) * O_ + o];
  out[b * O_ + o] = s;
}

// ---------------------------------------------------------------------------
extern "C" void kernel_launch(void* const* d_in, const int* in_sizes, int n_in,
                              void* d_out, int out_size, void* d_ws, size_t ws_size,
                              hipStream_t stream) {
  (void)in_sizes; (void)n_in; (void)out_size; (void)ws_size;
  const float* enc      = (const float*)d_in[0];
  // d_in[1] = enc_len : unused by the reference
  const float* dec_z    = (const float*)d_in[2];
  const float* att_prev = (const float*)d_in[3];
  const float* Wenc     = (const float*)d_in[4];
  const float* benc     = (const float*)d_in[5];
  const float* Wdec     = (const float*)d_in[6];
  const float* Watt     = (const float*)d_in[7];
  const float* conv_w   = (const float*)d_in[8];
  const float* gv       = (const float*)d_in[9];
  const float* Wo       = (const float*)d_in[10];
  const float* bo       = (const float*)d_in[11];

  float* out  = (float*)d_out;
  float* wout = out + B_ * O_;  // ws [H,B,T]

  char* wsb = (char*)d_ws;
  float*  e_buf   = (float*)(wsb);               // 1,024,000 B
  char*   convpad = wsb + 1024000;               // 8,192,000 B
  char*   wbs2    = wsb + 9216000;               //   524,288 B
  char*   wattb2  = wsb + 9740288;               //    16,384 B
  float*  addv4   = (float*)(wsb + 9756672);     //   131,072 B
  float2* msum    = (float2*)(wsb + 9887744);    //       512 B
  float*  partial = (float*)(wsb + 9888256);     // 6,553,600 B
  float*  p2      = (float*)(wsb + 16441856);    //   262,144 B
  char*   encbf   = wsb + 16704000;              // 65,536,000 B (bf16 enc)

  hipLaunchKernelGGL(k_prepconv, dim3(1281), dim3(256), 0, stream,
                     Wenc, Watt, dec_z, Wdec, benc, att_prev, conv_w,
                     wbs2, wattb2, addv4, convpad);
  hipLaunchKernelGGL(k_fused_e_mfma, dim3(1000), dim3(512), 0, stream,
                     enc, wbs2, convpad, wattb2, addv4, gv, encbf, e_buf);
  hipLaunchKernelGGL(k_msum, dim3(B_ * H_), dim3(256), 0, stream, e_buf, msum);
  hipLaunchKernelGGL(k_ctx, dim3(B_, TC_), dim3(512), 0, stream,
                     encbf, e_buf, msum, wout, partial);
  hipLaunchKernelGGL(k_out_part, dim3(B_, O_ / 256, 8), dim3(256), 0, stream, partial, Wo, p2);
  hipLaunchKernelGGL(k_out_fin, dim3(B_), dim3(512), 0, stream, p2, bo, out);
}